// Round 1
// baseline (1386.558 us; speedup 1.0000x reference)
//
#include <hip/hip_runtime.h>
#include <math.h>

#define NH     64
#define SQ     8
#define SKV    4096
#define DD     128
#define MM     128
#define CHUNK  256
#define NCHUNK (SKV / CHUNK)   // 16

// ws layout (floats)
#define OFF_QPT   0
#define OFF_PROJT (OFF_QPT + NH*MM*SQ)              // 65536
#define OFF_O     (OFF_PROJT + MM*DD)               // 81920
#define OFF_M     (OFF_O + NH*NCHUNK*SQ*DD)         // 1130496
#define OFF_L     (OFF_M + NH*NCHUNK*SQ)            // 1138688
// total = 1146880 floats = 4.59 MB of ws

// ---------------- kernel 1: qpT (q @ proj, stored [head][m][q]) + projT ----
__global__ __launch_bounds__(256) void k_prep(const float* __restrict__ query,
                                              const float* __restrict__ proj,
                                              float* __restrict__ ws) {
  float* qpT   = ws + OFF_QPT;
  float* projT = ws + OFF_PROJT;
  int b = blockIdx.x;
  if (b < NH) {
    __shared__ float qs[SQ * DD];
    const float* qrow = query + (size_t)b * SQ * DD;
    for (int i = threadIdx.x; i < SQ * DD; i += 256) qs[i] = qrow[i];
    __syncthreads();
    int j  = threadIdx.x & (MM - 1);
    int qh = threadIdx.x >> 7;          // 0..1 (wave-uniform)
    float a0 = 0.f, a1 = 0.f, a2 = 0.f, a3 = 0.f;
    for (int d = 0; d < DD; ++d) {
      float pv = proj[d * MM + j];
      a0 += qs[(qh + 0) * DD + d] * pv;
      a1 += qs[(qh + 2) * DD + d] * pv;
      a2 += qs[(qh + 4) * DD + d] * pv;
      a3 += qs[(qh + 6) * DD + d] * pv;
    }
    float* dst = qpT + ((size_t)b * MM + j) * SQ;
    dst[qh + 0] = a0; dst[qh + 2] = a1; dst[qh + 4] = a2; dst[qh + 6] = a3;
  } else {
    int g = (b - NH) * 256 + threadIdx.x;   // 0..16383
    int j = g >> 7, d = g & (DD - 1);
    projT[j * DD + d] = proj[d * MM + j];
  }
}

// ---------------- kernel 2: main (quantize keys, signs, scores, partial PV) --
__global__ __launch_bounds__(256) void k_attn(const float* __restrict__ keys,
                                              const float* __restrict__ values,
                                              const float* __restrict__ query,
                                              float* ws) {
  const float* qpT_g   = ws + OFF_QPT;
  const float* projT_g = ws + OFF_PROJT;
  float* o_part = ws + OFF_O;
  float* m_part = ws + OFF_M;
  float* l_part = ws + OFF_L;

  __shared__ float qs[SQ * DD];        // 4 KB  (query rows)
  __shared__ float qps[MM * SQ];       // 4 KB  (qp transposed: [m][q])
  __shared__ float vstat[CHUNK][2];    // 2 KB  (per-key vmin/vmax)
  union SmemU {                        // 32 KB, phase-reused
    float projT_h[64 * DD];            // phase 1: half of projT
    struct {
      float p[CHUNK][SQ];              // 8 KB   softmax numerators
      float red[4][SQ];                // 128 B  cross-wave reduce
      float oacc[4][SQ][DD];           // 16 KB  per-wave PV partials
    } ph2;
  };
  __shared__ SmemU u;

  const int tid  = threadIdx.x;
  const int lane = tid & 63;
  const int w    = tid >> 6;
  const int c    = blockIdx.x;   // chunk 0..15
  const int h    = blockIdx.y;   // head  0..63

  // ---- stage q, qpT, projT rows 0..63 ----
  {
    const float4* s1 = (const float4*)(query + (size_t)h * SQ * DD);
    ((float4*)qs)[tid] = s1[tid];                       // 256 float4 = 8x128
    const float4* s2 = (const float4*)(qpT_g + (size_t)h * MM * SQ);
    ((float4*)qps)[tid] = s2[tid];                      // 256 float4 = 128x8
    const float4* s3 = (const float4*)projT_g;
    float4* d3 = (float4*)u.projT_h;
    #pragma unroll
    for (int i = 0; i < 8; ++i) d3[tid + i * 256] = s3[tid + i * 256];
  }
  __syncthreads();

  // ---- phase 1a: load key row, quantize, q.k_hat dot, resid in regs ----
  const int key = c * CHUNK + tid;
  const float* krow = keys + ((size_t)h * SKV + key) * DD;
  const float step = 6.0f / 7.0f;

  float resid[DD];
  float a[SQ];
  #pragma unroll
  for (int q = 0; q < SQ; ++q) a[q] = 0.f;
  float res2 = 0.f;

  #pragma unroll
  for (int d4 = 0; d4 < DD / 4; ++d4) {
    float4 kv = ((const float4*)krow)[d4];
    float kk[4] = {kv.x, kv.y, kv.z, kv.w};
    float kh[4];
    #pragma unroll
    for (int e = 0; e < 4; ++e) {
      float t  = (kk[e] + 3.0f) / step;          // exact div: matches ref rounding
      float fi = fminf(fmaxf(rintf(t), 0.0f), 7.0f);
      kh[e] = fi * step - 3.0f;
      float r = kk[e] - kh[e];
      resid[d4 * 4 + e] = r;
      res2 += r * r;
    }
    #pragma unroll
    for (int q = 0; q < SQ; ++q) {
      float4 q4 = *(const float4*)(qs + q * DD + d4 * 4);   // LDS broadcast b128
      a[q] += q4.x * kh[0]; a[q] += q4.y * kh[1];
      a[q] += q4.z * kh[2]; a[q] += q4.w * kh[3];
    }
  }

  // ---- phase 1b: values row min/max scan (also prefetches rows into L2) ----
  {
    const float4* vrow = (const float4*)(values + ((size_t)h * SKV + key) * DD);
    float mn0 = 1e30f, mn1 = 1e30f, mx0 = -1e30f, mx1 = -1e30f;
    #pragma unroll 4
    for (int i = 0; i < DD / 4; ++i) {
      float4 vv = vrow[i];
      mn0 = fminf(mn0, fminf(vv.x, vv.y));
      mn1 = fminf(mn1, fminf(vv.z, vv.w));
      mx0 = fmaxf(mx0, fmaxf(vv.x, vv.y));
      mx1 = fmaxf(mx1, fmaxf(vv.z, vv.w));
    }
    vstat[tid][0] = fminf(mn0, mn1);
    vstat[tid][1] = fmaxf(mx0, mx1);
  }

  // ---- phase 1c: z = resid @ proj, y[q] += sign(z) * qp[q][m] ----
  float y[SQ];
  #pragma unroll
  for (int q = 0; q < SQ; ++q) y[q] = 0.f;

  #pragma unroll 1
  for (int half = 0; half < 2; ++half) {
    if (half == 1) {
      __syncthreads();                       // everyone done with rows 0..63
      const float4* src = (const float4*)(projT_g + 64 * DD);
      float4* dst = (float4*)u.projT_h;
      #pragma unroll
      for (int i = 0; i < 8; ++i) dst[tid + i * 256] = src[tid + i * 256];
      __syncthreads();
    }
    #pragma unroll 1
    for (int mmi = 0; mmi < 64; ++mmi) {
      const float4* prow = (const float4*)(u.projT_h + mmi * DD);
      float z0 = 0.f, z1 = 0.f, z2 = 0.f, z3 = 0.f;
      #pragma unroll
      for (int d4 = 0; d4 < DD / 4; ++d4) {
        float4 pv = prow[d4];                // LDS broadcast b128
        z0 += resid[4 * d4 + 0] * pv.x;
        z1 += resid[4 * d4 + 1] * pv.y;
        z2 += resid[4 * d4 + 2] * pv.z;
        z3 += resid[4 * d4 + 3] * pv.w;
      }
      float z = (z0 + z1) + (z2 + z3);
      float s = (z > 0.f) ? 1.f : ((z < 0.f) ? -1.f : 0.f);
      const int m = half * 64 + mmi;
      const float4* qpm = (const float4*)(qps + m * SQ);
      float4 pa = qpm[0], pb = qpm[1];
      y[0] += s * pa.x; y[1] += s * pa.y; y[2] += s * pa.z; y[3] += s * pa.w;
      y[4] += s * pb.x; y[5] += s * pb.y; y[6] += s * pb.z; y[7] += s * pb.w;
    }
  }

  // ---- scores ----
  const float qjl_coef = sqrtf(1.5707964f) * 0.0078125f;  // sqrt(pi/2)/128
  const float scale    = 1.0f / sqrtf(128.0f);
  const float rn = sqrtf(res2);
  float sc[SQ];
  #pragma unroll
  for (int q = 0; q < SQ; ++q) sc[q] = (a[q] + qjl_coef * y[q] * rn) * scale;

  // ---- chunk softmax (flash partials) ----
  float wred[SQ];
  #pragma unroll
  for (int q = 0; q < SQ; ++q) {
    float v = sc[q];
    #pragma unroll
    for (int off = 32; off > 0; off >>= 1) v = fmaxf(v, __shfl_xor(v, off));
    wred[q] = v;
  }
  __syncthreads();                 // all waves done reading u.projT_h
  if (lane == 0) {
    #pragma unroll
    for (int q = 0; q < SQ; ++q) u.ph2.red[w][q] = wred[q];
  }
  __syncthreads();
  float p[SQ];
  #pragma unroll
  for (int q = 0; q < SQ; ++q) {
    float M = fmaxf(fmaxf(u.ph2.red[0][q], u.ph2.red[1][q]),
                    fmaxf(u.ph2.red[2][q], u.ph2.red[3][q]));
    p[q] = expf(sc[q] - M);
    u.ph2.p[tid][q] = p[q];
  }
  if (tid < SQ) {
    float M = fmaxf(fmaxf(u.ph2.red[0][tid], u.ph2.red[1][tid]),
                    fmaxf(u.ph2.red[2][tid], u.ph2.red[3][tid]));
    m_part[((size_t)h * NCHUNK + c) * SQ + tid] = M;
  }
  #pragma unroll
  for (int q = 0; q < SQ; ++q) {
    float v = p[q];
    #pragma unroll
    for (int off = 32; off > 0; off >>= 1) v += __shfl_xor(v, off);
    wred[q] = v;
  }
  __syncthreads();                 // done reading red as max
  if (lane == 0) {
    #pragma unroll
    for (int q = 0; q < SQ; ++q) u.ph2.red[w][q] = wred[q];
  }
  __syncthreads();
  if (tid < SQ) {
    l_part[((size_t)h * NCHUNK + c) * SQ + tid] =
        u.ph2.red[0][tid] + u.ph2.red[1][tid] +
        u.ph2.red[2][tid] + u.ph2.red[3][tid];
  }

  // ---- PV: wave owns its 64 keys, lane <-> d pair (coalesced value loads) --
  float o[SQ][2];
  #pragma unroll
  for (int q = 0; q < SQ; ++q) { o[q][0] = 0.f; o[q][1] = 0.f; }
  const int d0 = 2 * lane;
  const float inv15 = 1.0f / 15.0f;   // feeds continuous value: mul ok (<=1ulp)
  #pragma unroll 1
  for (int kk = 0; kk < 64; ++kk) {
    const int kl = w * 64 + kk;
    const float2 vv = *(const float2*)(values + ((size_t)h * SKV + c * CHUNK + kl) * DD + d0);
    const float vmn = vstat[kl][0], vmx = vstat[kl][1];
    const float vr  = fmaxf(vmx - vmn, 1e-8f);
    float t0 = (vv.x - vmn) / vr * 15.0f;      // exact div: matches ref rounding
    float t1 = (vv.y - vmn) / vr * 15.0f;
    float i0 = fminf(fmaxf(rintf(t0), 0.f), 15.f);
    float i1 = fminf(fmaxf(rintf(t1), 0.f), 15.f);
    float vh0 = vmn + i0 * inv15 * (vmx - vmn);
    float vh1 = vmn + i1 * inv15 * (vmx - vmn);
    const float4* pk = (const float4*)(&u.ph2.p[kl][0]);  // broadcast
    float4 pa = pk[0], pb = pk[1];
    o[0][0] += pa.x * vh0; o[0][1] += pa.x * vh1;
    o[1][0] += pa.y * vh0; o[1][1] += pa.y * vh1;
    o[2][0] += pa.z * vh0; o[2][1] += pa.z * vh1;
    o[3][0] += pa.w * vh0; o[3][1] += pa.w * vh1;
    o[4][0] += pb.x * vh0; o[4][1] += pb.x * vh1;
    o[5][0] += pb.y * vh0; o[5][1] += pb.y * vh1;
    o[6][0] += pb.z * vh0; o[6][1] += pb.z * vh1;
    o[7][0] += pb.w * vh0; o[7][1] += pb.w * vh1;
  }
  #pragma unroll
  for (int q = 0; q < SQ; ++q) {
    u.ph2.oacc[w][q][d0]     = o[q][0];
    u.ph2.oacc[w][q][d0 + 1] = o[q][1];
  }
  __syncthreads();
  for (int i = tid; i < SQ * DD; i += 256) {
    int q = i >> 7, d = i & (DD - 1);
    float vsum = u.ph2.oacc[0][q][d] + u.ph2.oacc[1][q][d] +
                 u.ph2.oacc[2][q][d] + u.ph2.oacc[3][q][d];
    o_part[(((size_t)h * NCHUNK + c) * SQ + q) * DD + d] = vsum;
  }
}

// ---------------- kernel 3: combine chunk partials --------------------------
__global__ __launch_bounds__(128) void k_comb(const float* __restrict__ ws,
                                              float* __restrict__ out) {
  const float* o_part = ws + OFF_O;
  const float* m_part = ws + OFF_M;
  const float* l_part = ws + OFF_L;
  int hq = blockIdx.x;            // head*8 + q
  int h = hq >> 3, q = hq & 7;
  int d = threadIdx.x;
  float M = -1e30f;
  for (int cc = 0; cc < NCHUNK; ++cc)
    M = fmaxf(M, m_part[((size_t)h * NCHUNK + cc) * SQ + q]);
  float L = 0.f, acc = 0.f;
  for (int cc = 0; cc < NCHUNK; ++cc) {
    float mw = expf(m_part[((size_t)h * NCHUNK + cc) * SQ + q] - M);
    L   += mw * l_part[((size_t)h * NCHUNK + cc) * SQ + q];
    acc += mw * o_part[(((size_t)h * NCHUNK + cc) * SQ + q) * DD + d];
  }
  out[(size_t)hq * DD + d] = acc / L;
}

extern "C" void kernel_launch(void* const* d_in, const int* in_sizes, int n_in,
                              void* d_out, int out_size, void* d_ws, size_t ws_size,
                              hipStream_t stream) {
  const float* query  = (const float*)d_in[0];
  const float* keys   = (const float*)d_in[1];
  const float* values = (const float*)d_in[2];
  const float* proj   = (const float*)d_in[3];
  float* out = (float*)d_out;
  float* ws  = (float*)d_ws;

  k_prep<<<dim3(128), dim3(256), 0, stream>>>(query, proj, ws);
  k_attn<<<dim3(NCHUNK, NH), dim3(256), 0, stream>>>(keys, values, query, ws);
  k_comb<<<dim3(NH * SQ), dim3(128), 0, stream>>>(ws, out);
}

// Round 4
// 1317.814 us; speedup vs baseline: 1.0522x; 1.0522x over previous
//
#include <hip/hip_runtime.h>
#include <math.h>

#define NH     64
#define SQ     8
#define SKV    4096
#define DD     128
#define MM     128
#define CHUNK  256
#define NCHUNK (SKV / CHUNK)   // 16

// ws layout (floats)
#define OFF_QPT   0
#define OFF_PROJT (OFF_QPT + NH*MM*SQ)              // 65536
#define OFF_O     (OFF_PROJT + MM*DD)               // 81920
#define OFF_M     (OFF_O + NH*NCHUNK*SQ*DD)         // 1130496
#define OFF_L     (OFF_M + NH*NCHUNK*SQ)            // 1138688

// ---------------- kernel 1: qpT (q @ proj, stored [head][m][q]) + projT ----
__global__ __launch_bounds__(256) void k_prep(const float* __restrict__ query,
                                              const float* __restrict__ proj,
                                              float* __restrict__ ws) {
  float* qpT   = ws + OFF_QPT;
  float* projT = ws + OFF_PROJT;
  int b = blockIdx.x;
  if (b < NH) {
    __shared__ float qs[SQ * DD];
    const float* qrow = query + (size_t)b * SQ * DD;
    for (int i = threadIdx.x; i < SQ * DD; i += 256) qs[i] = qrow[i];
    __syncthreads();
    int j  = threadIdx.x & (MM - 1);
    int qh = threadIdx.x >> 7;          // 0..1 (wave-uniform)
    float a0 = 0.f, a1 = 0.f, a2 = 0.f, a3 = 0.f;
    for (int d = 0; d < DD; ++d) {
      float pv = proj[d * MM + j];
      a0 += qs[(qh + 0) * DD + d] * pv;
      a1 += qs[(qh + 2) * DD + d] * pv;
      a2 += qs[(qh + 4) * DD + d] * pv;
      a3 += qs[(qh + 6) * DD + d] * pv;
    }
    float* dst = qpT + ((size_t)b * MM + j) * SQ;
    dst[qh + 0] = a0; dst[qh + 2] = a1; dst[qh + 4] = a2; dst[qh + 6] = a3;
  } else {
    int g = (b - NH) * 256 + threadIdx.x;   // 0..16383
    int j = g >> 7, d = g & (DD - 1);
    projT[j * DD + d] = proj[d * MM + j];
  }
}

// ---------------- kernel 2: main --------------------------------------------
__global__ __launch_bounds__(256) void k_attn(const float* __restrict__ keys,
                                              const float* __restrict__ values,
                                              const float* __restrict__ query,
                                              float* ws) {
  const float* qpT_g   = ws + OFF_QPT;
  const float* projT_g = ws + OFF_PROJT;
  float* o_part = ws + OFF_O;
  float* m_part = ws + OFF_M;
  float* l_part = ws + OFF_L;

  __shared__ float qs[SQ * DD];        // 4 KB
  __shared__ float qps[MM * SQ];       // 4 KB
  __shared__ float projT_s[MM * DD];   // 64 KB (full projT, resident all kernel)
  __shared__ float p_s[CHUNK][SQ];     // 8 KB
  __shared__ float red[4][SQ];         // 128 B
  __shared__ float oacc[4][SQ][DD];    // 16 KB
  // total ~96 KB; VGPR-bound to 1 WG/CU anyway

  const int tid  = threadIdx.x;
  const int lane = tid & 63;
  const int w    = tid >> 6;
  const int c    = blockIdx.x;   // chunk 0..15
  const int h    = blockIdx.y;   // head  0..63

  // ---- stage q, qpT, full projT ----
  {
    const float4* s1 = (const float4*)(query + (size_t)h * SQ * DD);
    ((float4*)qs)[tid] = s1[tid];
    const float4* s2 = (const float4*)(qpT_g + (size_t)h * MM * SQ);
    ((float4*)qps)[tid] = s2[tid];
    const float4* s3 = (const float4*)projT_g;
    float4* d3 = (float4*)projT_s;
    #pragma unroll
    for (int i = 0; i < 16; ++i) d3[tid + i * 256] = s3[tid + i * 256];
  }
  __syncthreads();

  // ---- phase A: load key row, quantize, q.k_hat dot, resid in regs ----
  // segmented into 4 blocks of 8 float4 steps to bound register pressure
  const int key = c * CHUNK + tid;
  const float* krow = keys + ((size_t)h * SKV + key) * DD;
  const float4* kr4 = (const float4*)krow;
  const float step = 6.0f / 7.0f;

  float resid[DD];
  float a[SQ];
  #pragma unroll
  for (int q = 0; q < SQ; ++q) a[q] = 0.f;
  float res2 = 0.f;

#define PA_BLOCK(Q0)                                                        \
  _Pragma("unroll")                                                         \
  for (int d4 = (Q0); d4 < (Q0) + 8; ++d4) {                                \
    float4 kv = kr4[d4];                                                    \
    float t0 = (kv.x + 3.0f) / step, t1 = (kv.y + 3.0f) / step;             \
    float t2 = (kv.z + 3.0f) / step, t3 = (kv.w + 3.0f) / step;             \
    float f0 = fminf(fmaxf(rintf(t0), 0.f), 7.f);                           \
    float f1 = fminf(fmaxf(rintf(t1), 0.f), 7.f);                           \
    float f2 = fminf(fmaxf(rintf(t2), 0.f), 7.f);                           \
    float f3 = fminf(fmaxf(rintf(t3), 0.f), 7.f);                           \
    float h0 = f0 * step - 3.0f, h1 = f1 * step - 3.0f;                     \
    float h2 = f2 * step - 3.0f, h3 = f3 * step - 3.0f;                     \
    float r0 = kv.x - h0, r1 = kv.y - h1, r2 = kv.z - h2, r3 = kv.w - h3;   \
    resid[4 * d4 + 0] = r0; resid[4 * d4 + 1] = r1;                         \
    resid[4 * d4 + 2] = r2; resid[4 * d4 + 3] = r3;                         \
    res2 += r0 * r0; res2 += r1 * r1; res2 += r2 * r2; res2 += r3 * r3;     \
    _Pragma("unroll")                                                       \
    for (int q = 0; q < SQ; ++q) {                                          \
      float4 q4 = *(const float4*)(qs + q * DD + 4 * d4);                   \
      a[q] = fmaf(q4.x, h0, fmaf(q4.y, h1, fmaf(q4.z, h2,                   \
             fmaf(q4.w, h3, a[q]))));                                       \
    }                                                                       \
  }

  PA_BLOCK(0)
  __builtin_amdgcn_sched_barrier(0);
  PA_BLOCK(8)
  __builtin_amdgcn_sched_barrier(0);
  PA_BLOCK(16)
  __builtin_amdgcn_sched_barrier(0);
  PA_BLOCK(24)
  __builtin_amdgcn_sched_barrier(0);

  // ---- phase C: z = resid . projT[m], y[q] += sign(z) * qp[m][q] ----
  float y[SQ];
  #pragma unroll
  for (int q = 0; q < SQ; ++q) y[q] = 0.f;

  #pragma unroll 1
  for (int m = 0; m < MM; ++m) {
    const float4* prow4 = (const float4*)(projT_s + m * DD);
    float z0 = 0.f, z1 = 0.f, z2 = 0.f, z3 = 0.f;
    #pragma unroll
    for (int d4 = 0; d4 < 16; ++d4) {
      float4 pv = prow4[d4];
      z0 = fmaf(resid[4 * d4 + 0], pv.x, z0);
      z1 = fmaf(resid[4 * d4 + 1], pv.y, z1);
      z2 = fmaf(resid[4 * d4 + 2], pv.z, z2);
      z3 = fmaf(resid[4 * d4 + 3], pv.w, z3);
    }
    __builtin_amdgcn_sched_barrier(0);
    #pragma unroll
    for (int d4 = 16; d4 < 32; ++d4) {
      float4 pv = prow4[d4];
      z0 = fmaf(resid[4 * d4 + 0], pv.x, z0);
      z1 = fmaf(resid[4 * d4 + 1], pv.y, z1);
      z2 = fmaf(resid[4 * d4 + 2], pv.z, z2);
      z3 = fmaf(resid[4 * d4 + 3], pv.w, z3);
    }
    float zz = (z0 + z1) + (z2 + z3);
    float s = (zz > 0.f) ? 1.f : ((zz < 0.f) ? -1.f : 0.f);
    const float4* qpm = (const float4*)(qps + m * SQ);
    float4 pa = qpm[0], pb = qpm[1];
    y[0] = fmaf(s, pa.x, y[0]); y[1] = fmaf(s, pa.y, y[1]);
    y[2] = fmaf(s, pa.z, y[2]); y[3] = fmaf(s, pa.w, y[3]);
    y[4] = fmaf(s, pb.x, y[4]); y[5] = fmaf(s, pb.y, y[5]);
    y[6] = fmaf(s, pb.z, y[6]); y[7] = fmaf(s, pb.w, y[7]);
  }

  // ---- scores ----
  const float qjl_coef = sqrtf(1.5707964f) * 0.0078125f;  // sqrt(pi/2)/128
  const float scale    = 1.0f / sqrtf(128.0f);
  const float rn = sqrtf(res2);
  float sc[SQ];
  #pragma unroll
  for (int q = 0; q < SQ; ++q) sc[q] = (a[q] + qjl_coef * y[q] * rn) * scale;

  // ---- chunk softmax (flash partials) ----
  float wred[SQ];
  #pragma unroll
  for (int q = 0; q < SQ; ++q) {
    float v = sc[q];
    #pragma unroll
    for (int off = 32; off > 0; off >>= 1) v = fmaxf(v, __shfl_xor(v, off));
    wred[q] = v;
  }
  if (lane == 0) {
    #pragma unroll
    for (int q = 0; q < SQ; ++q) red[w][q] = wred[q];
  }
  __syncthreads();
  float p[SQ];
  #pragma unroll
  for (int q = 0; q < SQ; ++q) {
    float M = fmaxf(fmaxf(red[0][q], red[1][q]), fmaxf(red[2][q], red[3][q]));
    p[q] = expf(sc[q] - M);
    p_s[tid][q] = p[q];
  }
  if (tid < SQ) {
    float M = fmaxf(fmaxf(red[0][tid], red[1][tid]),
                    fmaxf(red[2][tid], red[3][tid]));
    m_part[((size_t)h * NCHUNK + c) * SQ + tid] = M;
  }
  #pragma unroll
  for (int q = 0; q < SQ; ++q) {
    float v = p[q];
    #pragma unroll
    for (int off = 32; off > 0; off >>= 1) v += __shfl_xor(v, off);
    wred[q] = v;
  }
  __syncthreads();                 // red max-reads + p_s writes complete
  if (lane == 0) {
    #pragma unroll
    for (int q = 0; q < SQ; ++q) red[w][q] = wred[q];
  }
  __syncthreads();
  if (tid < SQ) {
    l_part[((size_t)h * NCHUNK + c) * SQ + tid] =
        red[0][tid] + red[1][tid] + red[2][tid] + red[3][tid];
  }

  // ---- PV: wave owns its 64 keys, lane <-> d pair; in-loop minmax reduce ----
  float o[SQ][2];
  #pragma unroll
  for (int q = 0; q < SQ; ++q) { o[q][0] = 0.f; o[q][1] = 0.f; }
  const int d0 = 2 * lane;
  const float inv15 = 1.0f / 15.0f;
  #pragma unroll 2
  for (int kk = 0; kk < 64; ++kk) {
    const int kl = w * 64 + kk;
    const float2 vv = *(const float2*)(values +
        ((size_t)h * SKV + c * CHUNK + kl) * DD + d0);
    // full-row min/max via wave reduction (replaces separate values pass)
    float mn = fminf(vv.x, vv.y), mx = fmaxf(vv.x, vv.y);
    #pragma unroll
    for (int off = 32; off > 0; off >>= 1) {
      mn = fminf(mn, __shfl_xor(mn, off));
      mx = fmaxf(mx, __shfl_xor(mx, off));
    }
    const float vr = fmaxf(mx - mn, 1e-8f);
    float t0 = (vv.x - mn) / vr * 15.0f;
    float t1 = (vv.y - mn) / vr * 15.0f;
    float i0 = fminf(fmaxf(rintf(t0), 0.f), 15.f);
    float i1 = fminf(fmaxf(rintf(t1), 0.f), 15.f);
    float vh0 = mn + i0 * inv15 * (mx - mn);
    float vh1 = mn + i1 * inv15 * (mx - mn);
    const float4* pk = (const float4*)(&p_s[kl][0]);   // broadcast
    float4 pa = pk[0], pb = pk[1];
    o[0][0] = fmaf(pa.x, vh0, o[0][0]); o[0][1] = fmaf(pa.x, vh1, o[0][1]);
    o[1][0] = fmaf(pa.y, vh0, o[1][0]); o[1][1] = fmaf(pa.y, vh1, o[1][1]);
    o[2][0] = fmaf(pa.z, vh0, o[2][0]); o[2][1] = fmaf(pa.z, vh1, o[2][1]);
    o[3][0] = fmaf(pa.w, vh0, o[3][0]); o[3][1] = fmaf(pa.w, vh1, o[3][1]);
    o[4][0] = fmaf(pb.x, vh0, o[4][0]); o[4][1] = fmaf(pb.x, vh1, o[4][1]);
    o[5][0] = fmaf(pb.y, vh0, o[5][0]); o[5][1] = fmaf(pb.y, vh1, o[5][1]);
    o[6][0] = fmaf(pb.z, vh0, o[6][0]); o[6][1] = fmaf(pb.z, vh1, o[6][1]);
    o[7][0] = fmaf(pb.w, vh0, o[7][0]); o[7][1] = fmaf(pb.w, vh1, o[7][1]);
  }
  #pragma unroll
  for (int q = 0; q < SQ; ++q) {
    oacc[w][q][d0]     = o[q][0];
    oacc[w][q][d0 + 1] = o[q][1];
  }
  __syncthreads();
  for (int i = tid; i < SQ * DD; i += 256) {
    int q = i >> 7, d = i & (DD - 1);
    float vsum = oacc[0][q][d] + oacc[1][q][d] +
                 oacc[2][q][d] + oacc[3][q][d];
    o_part[(((size_t)h * NCHUNK + c) * SQ + q) * DD + d] = vsum;
  }
}

// ---------------- kernel 3: combine chunk partials --------------------------
__global__ __launch_bounds__(128) void k_comb(const float* __restrict__ ws,
                                              float* __restrict__ out) {
  const float* o_part = ws + OFF_O;
  const float* m_part = ws + OFF_M;
  const float* l_part = ws + OFF_L;
  int hq = blockIdx.x;            // head*8 + q
  int h = hq >> 3, q = hq & 7;
  int d = threadIdx.x;
  float M = -1e30f;
  for (int cc = 0; cc < NCHUNK; ++cc)
    M = fmaxf(M, m_part[((size_t)h * NCHUNK + cc) * SQ + q]);
  float L = 0.f, acc = 0.f;
  for (int cc = 0; cc < NCHUNK; ++cc) {
    float mw = expf(m_part[((size_t)h * NCHUNK + cc) * SQ + q] - M);
    L   += mw * l_part[((size_t)h * NCHUNK + cc) * SQ + q];
    acc += mw * o_part[(((size_t)h * NCHUNK + cc) * SQ + q) * DD + d];
  }
  out[(size_t)hq * DD + d] = acc / L;
}

extern "C" void kernel_launch(void* const* d_in, const int* in_sizes, int n_in,
                              void* d_out, int out_size, void* d_ws, size_t ws_size,
                              hipStream_t stream) {
  const float* query  = (const float*)d_in[0];
  const float* keys   = (const float*)d_in[1];
  const float* values = (const float*)d_in[2];
  const float* proj   = (const float*)d_in[3];
  float* out = (float*)d_out;
  float* ws  = (float*)d_ws;

  k_prep<<<dim3(128), dim3(256), 0, stream>>>(query, proj, ws);
  k_attn<<<dim3(NCHUNK, NH), dim3(256), 0, stream>>>(keys, values, query, ws);
  k_comb<<<dim3(NH * SQ), dim3(128), 0, stream>>>(ws, out);
}